// Round 10
// baseline (230.718 us; speedup 1.0000x reference)
//
#include <hip/hip_runtime.h>
#include <hip/hip_bf16.h>

#define N_NODES 10000
#define N_EDGES 320000
#define N_GRAPHS 64
#define DIM 256
#define ADIM 118
#define OUTD 100
#define CAP 192          // fixed CSR slots per node (mean degree 32, max ~66)

typedef short bf8_t __attribute__((ext_vector_type(8)));
typedef float f4_t  __attribute__((ext_vector_type(4)));

__device__ __forceinline__ unsigned short f2bf(float f) {
    unsigned u = __float_as_uint(f);
    u += 0x7FFFu + ((u >> 16) & 1u);   // round-to-nearest-even
    return (unsigned short)(u >> 16);
}
__device__ __forceinline__ float bf2f(unsigned short s) {
    return __uint_as_float(((unsigned)s) << 16);
}

// ---------- setup: weight conversion + cursor init + feat zero ----------
__global__ __launch_bounds__(256) void convW_k(
    const float* __restrict__ Wn, const float* __restrict__ Wg,
    unsigned short* __restrict__ WnT, unsigned short* __restrict__ WgT,
    int* __restrict__ cursor, float* __restrict__ feat) {
    int i = blockIdx.x * 256 + threadIdx.x;   // grid 640*256 = 163840
    if (i < 32768) {
        int c = i >> 7, k = i & 127;
        WnT[i] = (k < ADIM) ? f2bf(Wn[k * DIM + c]) : (unsigned short)0;
    } else {
        int j = i - 32768;
        int l = j >> 16, rem = j & 65535;
        int c = rem >> 8, k = rem & 255;
        WgT[j] = f2bf(Wg[l * 65536 + k * DIM + c]);
    }
    if (i < N_NODES) cursor[i] = i * CAP;
    if (i < N_GRAPHS * DIM) feat[i] = 0.f;
}

// ---------- CSR fill (fixed stride) ----------
__global__ __launch_bounds__(256) void fill_k(
    const int* __restrict__ src, const int* __restrict__ dst,
    const float* __restrict__ len, int* __restrict__ cursor,
    int2* __restrict__ epack) {
    int j = blockIdx.x * 256 + threadIdx.x;
    if (j >= N_EDGES) return;
    int d = dst[j];
    int pos = atomicAdd(&cursor[d], 1);
    if (pos < d * CAP + CAP)
        epack[pos] = make_int2(src[j], __float_as_int(len[j]));
}

// ---------- node embedding via MFMA: h = bf16(an @ W_node + b_node) ----------
#define AST 136   // LDS row stride (ushorts)
__global__ __launch_bounds__(256) void node_embed_k(
    const float* __restrict__ an, const unsigned short* __restrict__ WnT,
    const float* __restrict__ bn, unsigned short* __restrict__ hbf) {
    __shared__ unsigned short xs[16 * AST];
    const int base = blockIdx.x * 16;
    const int tid = threadIdx.x;
    for (int i = tid; i < 16 * (AST - ADIM); i += 256) {
        int r = i / (AST - ADIM);
        int c = i - r * (AST - ADIM);
        xs[r * AST + ADIM + c] = 0;
    }
    for (int i = tid; i < 16 * ADIM; i += 256) {
        int r = i / ADIM;
        int c = i - r * ADIM;
        xs[r * AST + c] = f2bf(an[(size_t)(base + r) * ADIM + c]);
    }
    __syncthreads();
    const int wave = tid >> 6, lane = tid & 63;
    const int m = lane & 15, quad = lane >> 4;
    bf8_t afrag[4];
    #pragma unroll
    for (int s = 0; s < 4; ++s)
        afrag[s] = *(const bf8_t*)&xs[m * AST + s * 32 + quad * 8];
    const int colbase = wave * 64;
    f4_t acc[4];
    #pragma unroll
    for (int ct = 0; ct < 4; ++ct) acc[ct] = (f4_t){0.f, 0.f, 0.f, 0.f};
    #pragma unroll
    for (int ct = 0; ct < 4; ++ct) {
        const unsigned short* wp = WnT + (size_t)(colbase + ct * 16 + m) * 128 + quad * 8;
        #pragma unroll
        for (int s = 0; s < 4; ++s) {
            bf8_t bfrag = *(const bf8_t*)(wp + s * 32);
            acc[ct] = __builtin_amdgcn_mfma_f32_16x16x32_bf16(afrag[s], bfrag, acc[ct], 0, 0, 0);
        }
    }
    #pragma unroll
    for (int ct = 0; ct < 4; ++ct) {
        int col = colbase + ct * 16 + m;
        float bb = bn[col];
        #pragma unroll
        for (int r = 0; r < 4; ++r)
            hbf[(size_t)(base + quad * 4 + r) * DIM + col] = f2bf(acc[ct][r] + bb);
    }
}

// ---------- gather-aggregate: one BLOCK per node, 4 waves split the edge list ----------
// Each wave: contiguous quarter of the edge list, full 256-d rows (ushort4/lane).
// Serial chain per wave ~8 edges; partials reduced via LDS.
__global__ __launch_bounds__(256) void gather_k(
    const unsigned short* __restrict__ hbf, const int* __restrict__ cursor,
    const int2* __restrict__ epack, const float* __restrict__ We,
    const float* __restrict__ be, const float* __restrict__ epsp, int layer,
    unsigned short* __restrict__ xbf) {
    __shared__ float sacc[4][DIM];
    const int node = blockIdx.x;
    const int wave = threadIdx.x >> 6, lane = threadIdx.x & 63;
    const int c = lane << 2;
    const float4 w  = *(const float4*)(We + c);
    const float4 bb = *(const float4*)(be + c);
    const int lo = node * CAP;
    const int cnt = min(cursor[node] - lo, CAP);     // wave-uniform
    const int chunk = (cnt + 3) >> 2;
    const int t0 = wave * chunk;
    const int t1 = min(cnt, t0 + chunk);
    float4 acc = {0.f, 0.f, 0.f, 0.f};
    const int2* ep = epack + lo;
    int t = t0;
    for (; t + 3 < t1; t += 4) {
        int2 p0 = ep[t], p1 = ep[t + 1], p2 = ep[t + 2], p3 = ep[t + 3];
        ushort4 a0 = *(const ushort4*)(hbf + (size_t)p0.x * DIM + c);
        ushort4 a1 = *(const ushort4*)(hbf + (size_t)p1.x * DIM + c);
        ushort4 a2 = *(const ushort4*)(hbf + (size_t)p2.x * DIM + c);
        ushort4 a3 = *(const ushort4*)(hbf + (size_t)p3.x * DIM + c);
        float l0 = __int_as_float(p0.y), l1 = __int_as_float(p1.y);
        float l2 = __int_as_float(p2.y), l3 = __int_as_float(p3.y);
        acc.x += fmaxf(bf2f(a0.x) + fmaf(l0, w.x, bb.x), 0.f);
        acc.y += fmaxf(bf2f(a0.y) + fmaf(l0, w.y, bb.y), 0.f);
        acc.z += fmaxf(bf2f(a0.z) + fmaf(l0, w.z, bb.z), 0.f);
        acc.w += fmaxf(bf2f(a0.w) + fmaf(l0, w.w, bb.w), 0.f);
        acc.x += fmaxf(bf2f(a1.x) + fmaf(l1, w.x, bb.x), 0.f);
        acc.y += fmaxf(bf2f(a1.y) + fmaf(l1, w.y, bb.y), 0.f);
        acc.z += fmaxf(bf2f(a1.z) + fmaf(l1, w.z, bb.z), 0.f);
        acc.w += fmaxf(bf2f(a1.w) + fmaf(l1, w.w, bb.w), 0.f);
        acc.x += fmaxf(bf2f(a2.x) + fmaf(l2, w.x, bb.x), 0.f);
        acc.y += fmaxf(bf2f(a2.y) + fmaf(l2, w.y, bb.y), 0.f);
        acc.z += fmaxf(bf2f(a2.z) + fmaf(l2, w.z, bb.z), 0.f);
        acc.w += fmaxf(bf2f(a2.w) + fmaf(l2, w.w, bb.w), 0.f);
        acc.x += fmaxf(bf2f(a3.x) + fmaf(l3, w.x, bb.x), 0.f);
        acc.y += fmaxf(bf2f(a3.y) + fmaf(l3, w.y, bb.y), 0.f);
        acc.z += fmaxf(bf2f(a3.z) + fmaf(l3, w.z, bb.z), 0.f);
        acc.w += fmaxf(bf2f(a3.w) + fmaf(l3, w.w, bb.w), 0.f);
    }
    for (; t < t1; ++t) {
        int2 p0 = ep[t];
        ushort4 a0 = *(const ushort4*)(hbf + (size_t)p0.x * DIM + c);
        float l0 = __int_as_float(p0.y);
        acc.x += fmaxf(bf2f(a0.x) + fmaf(l0, w.x, bb.x), 0.f);
        acc.y += fmaxf(bf2f(a0.y) + fmaf(l0, w.y, bb.y), 0.f);
        acc.z += fmaxf(bf2f(a0.z) + fmaf(l0, w.z, bb.z), 0.f);
        acc.w += fmaxf(bf2f(a0.w) + fmaf(l0, w.w, bb.w), 0.f);
    }
    *(float4*)&sacc[wave][c] = acc;
    __syncthreads();
    // epilogue: one dim per thread
    const int d = threadIdx.x;
    float s = sacc[0][d] + sacc[1][d] + sacc[2][d] + sacc[3][d];
    const float eps1 = 1.f + epsp[layer];
    float hv = bf2f(hbf[(size_t)node * DIM + d]);
    xbf[(size_t)node * DIM + d] = f2bf(fmaf(eps1, hv, s));
}

// ---------- MFMA node update: block = 16 rows x 128 cols (grid 1250) ----------
#define XST 264   // LDS row stride (ushorts)
__global__ __launch_bounds__(256) void update_k(
    const unsigned short* __restrict__ xbf,
    const unsigned short* __restrict__ WT, const float* __restrict__ b,
    unsigned short* __restrict__ hout,
    const int* __restrict__ gid, float* __restrict__ feat, int do_pool) {
    __shared__ unsigned short xs[16 * XST];
    __shared__ int gids[16];
    const int rb = blockIdx.x >> 1;
    const int halfc = blockIdx.x & 1;
    const int base = rb * 16;
    const int tid = threadIdx.x;
    #pragma unroll
    for (int cch = tid; cch < 512; cch += 256) {     // 16 rows x 32 chunks of 8
        int rr = cch >> 5, k0 = (cch & 31) * 8;
        *(bf8_t*)&xs[rr * XST + k0] = *(const bf8_t*)(xbf + (size_t)(base + rr) * DIM + k0);
    }
    if (do_pool && tid < 16) gids[tid] = gid[base + tid];
    __syncthreads();
    const int wave = tid >> 6, lane = tid & 63;
    const int m = lane & 15, quad = lane >> 4;
    bf8_t afrag[8];
    #pragma unroll
    for (int s = 0; s < 8; ++s)
        afrag[s] = *(const bf8_t*)&xs[m * XST + s * 32 + quad * 8];
    const int colbase = halfc * 128 + wave * 32;
    f4_t acc[2];
    #pragma unroll
    for (int ct = 0; ct < 2; ++ct) acc[ct] = (f4_t){0.f, 0.f, 0.f, 0.f};
    #pragma unroll
    for (int ct = 0; ct < 2; ++ct) {
        const unsigned short* wp = WT + (size_t)(colbase + ct * 16 + m) * DIM + quad * 8;
        #pragma unroll
        for (int s = 0; s < 8; ++s) {
            bf8_t bfrag = *(const bf8_t*)(wp + s * 32);
            acc[ct] = __builtin_amdgcn_mfma_f32_16x16x32_bf16(afrag[s], bfrag, acc[ct], 0, 0, 0);
        }
    }
    if (!do_pool) {
        #pragma unroll
        for (int ct = 0; ct < 2; ++ct) {
            int col = colbase + ct * 16 + m;
            float bb = b[col];
            #pragma unroll
            for (int r = 0; r < 4; ++r)
                hout[(size_t)(base + quad * 4 + r) * DIM + col] = f2bf(acc[ct][r] + bb);
        }
    } else {
        #pragma unroll
        for (int ct = 0; ct < 2; ++ct) {
            int col = colbase + ct * 16 + m;
            float bb = b[col];
            float run = 0.f;
            int cur = gids[quad * 4];
            #pragma unroll
            for (int r = 0; r < 4; ++r) {
                int g = gids[quad * 4 + r];
                if (g != cur) {
                    atomicAdd(&feat[(size_t)cur * DIM + col], run);
                    run = 0.f;
                    cur = g;
                }
                run += acc[ct][r] + bb;
            }
            atomicAdd(&feat[(size_t)cur * DIM + col], run);
        }
    }
}

// ---------- fused global minmax + normalize + head (one block per graph) ----------
__global__ __launch_bounds__(256) void headmm_k(
    const float* __restrict__ feat, const float* __restrict__ Wm,
    const float* __restrict__ bm, const float* __restrict__ epsp,
    float* __restrict__ out) {
    __shared__ float frow[DIM];
    __shared__ float smn[4], smx[4], sMn, sMx;
    const int g = blockIdx.x;
    const int tid = threadIdx.x;
    float mn = 3.4e38f, mx = -3.4e38f;
    for (int i = tid; i < N_GRAPHS * DIM; i += 256) {
        float v = feat[i];
        mn = fminf(mn, v);
        mx = fmaxf(mx, v);
    }
    frow[tid] = feat[g * DIM + tid];
    #pragma unroll
    for (int off = 32; off > 0; off >>= 1) {
        mn = fminf(mn, __shfl_down(mn, off, 64));
        mx = fmaxf(mx, __shfl_down(mx, off, 64));
    }
    const int wave = tid >> 6, lane = tid & 63;
    if (lane == 0) { smn[wave] = mn; smx[wave] = mx; }
    __syncthreads();
    if (tid == 0) {
        sMn = fminf(fminf(smn[0], smn[1]), fminf(smn[2], smn[3]));
        sMx = fmaxf(fmaxf(smx[0], smx[1]), fmaxf(smx[2], smx[3]));
    }
    __syncthreads();
    if (tid < OUTD) {
        const float mnv = sMn;
        const float inv = 1.f / (epsp[0] + sMx - mnv);
        float acc = 0.f;
        for (int d = 0; d < DIM; ++d)
            acc += (frow[d] - mnv) * Wm[d * OUTD + tid];
        out[g * OUTD + tid] = acc * inv + bm[tid];
    }
}

extern "C" void kernel_launch(void* const* d_in, const int* in_sizes, int n_in,
                              void* d_out, int out_size, void* d_ws, size_t ws_size,
                              hipStream_t stream) {
    const float* atomic_num = (const float*)d_in[0];
    const float* length     = (const float*)d_in[1];
    const int*   src        = (const int*)d_in[2];
    const int*   dst        = (const int*)d_in[3];
    const int*   gid        = (const int*)d_in[4];
    const float* W_node     = (const float*)d_in[5];
    const float* b_node     = (const float*)d_in[6];
    const float* W_edge     = (const float*)d_in[7];
    const float* b_edge     = (const float*)d_in[8];
    const float* gine_eps   = (const float*)d_in[9];
    const float* W_gnn      = (const float*)d_in[10];
    const float* b_gnn      = (const float*)d_in[11];
    const float* eps_param  = (const float*)d_in[12];
    const float* W_mlp      = (const float*)d_in[13];
    const float* b_mlp      = (const float*)d_in[14];
    float* out = (float*)d_out;

    // workspace (~31 MB)
    float* feat = (float*)d_ws;                               // G*D
    int* cursor = (int*)(feat + (size_t)N_GRAPHS * DIM);      // N
    int2* epack = (int2*)(cursor + N_NODES + 4);              // N*CAP
    unsigned short* hbf0 = (unsigned short*)(epack + (size_t)N_NODES * CAP); // [N][256]
    unsigned short* hbf1 = hbf0 + (size_t)N_NODES * DIM;      // [N][256]
    unsigned short* xbf  = hbf1 + (size_t)N_NODES * DIM;      // [N][256]
    unsigned short* WnT  = xbf + (size_t)N_NODES * DIM;       // 256*128
    unsigned short* WgT  = WnT + 256 * 128;                   // 2*256*256

    convW_k<<<640, 256, 0, stream>>>(W_node, W_gnn, WnT, WgT, cursor, feat);
    fill_k<<<N_EDGES / 256, 256, 0, stream>>>(src, dst, length, cursor, epack);
    node_embed_k<<<N_NODES / 16, 256, 0, stream>>>(atomic_num, WnT, b_node, hbf0);

    // GINE layer 0: hbf0 -> xbf -> hbf1
    gather_k<<<N_NODES, 256, 0, stream>>>(
        hbf0, cursor, epack, W_edge, b_edge, gine_eps, 0, xbf);
    update_k<<<(N_NODES / 16) * 2, 256, 0, stream>>>(
        xbf, WgT, b_gnn, hbf1, gid, feat, 0);
    // GINE layer 1: hbf1 -> xbf -> feat (pooled)
    gather_k<<<N_NODES, 256, 0, stream>>>(
        hbf1, cursor, epack, W_edge, b_edge, gine_eps, 1, xbf);
    update_k<<<(N_NODES / 16) * 2, 256, 0, stream>>>(
        xbf, WgT + 256 * 256, b_gnn + DIM, hbf0, gid, feat, 1);

    // fused minmax + normalize + head
    headmm_k<<<N_GRAPHS, 256, 0, stream>>>(feat, W_mlp, b_mlp, eps_param, out);
}

// Round 11
// 217.311 us; speedup vs baseline: 1.0617x; 1.0617x over previous
//
#include <hip/hip_runtime.h>
#include <hip/hip_bf16.h>

#define N_NODES 10000
#define N_EDGES 320000
#define N_GRAPHS 64
#define DIM 256
#define ADIM 118
#define OUTD 100
#define CAP 192          // fixed CSR slots per node (mean degree 32, max ~66)

typedef short bf8_t __attribute__((ext_vector_type(8)));
typedef float f4_t  __attribute__((ext_vector_type(4)));

__device__ __forceinline__ unsigned short f2bf(float f) {
    unsigned u = __float_as_uint(f);
    u += 0x7FFFu + ((u >> 16) & 1u);   // round-to-nearest-even
    return (unsigned short)(u >> 16);
}
__device__ __forceinline__ float bf2f(unsigned short s) {
    return __uint_as_float(((unsigned)s) << 16);
}

// ---------- setup: weight conversion + cursor init + feat zero ----------
__global__ __launch_bounds__(256) void convW_k(
    const float* __restrict__ Wn, const float* __restrict__ Wg,
    unsigned short* __restrict__ WnT, unsigned short* __restrict__ WgT,
    int* __restrict__ cursor, float* __restrict__ feat) {
    int i = blockIdx.x * 256 + threadIdx.x;   // grid 640*256 = 163840
    if (i < 32768) {
        int c = i >> 7, k = i & 127;
        WnT[i] = (k < ADIM) ? f2bf(Wn[k * DIM + c]) : (unsigned short)0;
    } else {
        int j = i - 32768;
        int l = j >> 16, rem = j & 65535;
        int c = rem >> 8, k = rem & 255;
        WgT[j] = f2bf(Wg[l * 65536 + k * DIM + c]);
    }
    if (i < N_NODES) cursor[i] = i * CAP;
    if (i < N_GRAPHS * DIM) feat[i] = 0.f;
}

// ---------- CSR fill (fixed stride) ----------
__global__ __launch_bounds__(256) void fill_k(
    const int* __restrict__ src, const int* __restrict__ dst,
    const float* __restrict__ len, int* __restrict__ cursor,
    int2* __restrict__ epack) {
    int j = blockIdx.x * 256 + threadIdx.x;
    if (j >= N_EDGES) return;
    int d = dst[j];
    int pos = atomicAdd(&cursor[d], 1);
    if (pos < d * CAP + CAP)
        epack[pos] = make_int2(src[j], __float_as_int(len[j]));
}

// ---------- node embedding via MFMA: h = bf16(an @ W_node + b_node) ----------
#define AST 136   // LDS row stride (ushorts)
__global__ __launch_bounds__(256) void node_embed_k(
    const float* __restrict__ an, const unsigned short* __restrict__ WnT,
    const float* __restrict__ bn, unsigned short* __restrict__ hbf) {
    __shared__ unsigned short xs[16 * AST];
    const int base = blockIdx.x * 16;
    const int tid = threadIdx.x;
    for (int i = tid; i < 16 * (AST - ADIM); i += 256) {
        int r = i / (AST - ADIM);
        int c = i - r * (AST - ADIM);
        xs[r * AST + ADIM + c] = 0;
    }
    for (int i = tid; i < 16 * ADIM; i += 256) {
        int r = i / ADIM;
        int c = i - r * ADIM;
        xs[r * AST + c] = f2bf(an[(size_t)(base + r) * ADIM + c]);
    }
    __syncthreads();
    const int wave = tid >> 6, lane = tid & 63;
    const int m = lane & 15, quad = lane >> 4;
    bf8_t afrag[4];
    #pragma unroll
    for (int s = 0; s < 4; ++s)
        afrag[s] = *(const bf8_t*)&xs[m * AST + s * 32 + quad * 8];
    const int colbase = wave * 64;
    f4_t acc[4];
    #pragma unroll
    for (int ct = 0; ct < 4; ++ct) acc[ct] = (f4_t){0.f, 0.f, 0.f, 0.f};
    #pragma unroll
    for (int ct = 0; ct < 4; ++ct) {
        const unsigned short* wp = WnT + (size_t)(colbase + ct * 16 + m) * 128 + quad * 8;
        #pragma unroll
        for (int s = 0; s < 4; ++s) {
            bf8_t bfrag = *(const bf8_t*)(wp + s * 32);
            acc[ct] = __builtin_amdgcn_mfma_f32_16x16x32_bf16(afrag[s], bfrag, acc[ct], 0, 0, 0);
        }
    }
    #pragma unroll
    for (int ct = 0; ct < 4; ++ct) {
        int col = colbase + ct * 16 + m;
        float bb = bn[col];
        #pragma unroll
        for (int r = 0; r < 4; ++r)
            hbf[(size_t)(base + quad * 4 + r) * DIM + col] = f2bf(acc[ct][r] + bb);
    }
}

// ---------- gather-aggregate: wave per node, TWO edges per iteration ----------
// lanes 0-31 -> edge t, lanes 32-63 -> edge t+1; each lane loads 16B (8 dims).
// Scalar (SGPR) edge-record reads; cross-half combine via 8 shfls at the end.
__global__ __launch_bounds__(256) void gather_k(
    const unsigned short* __restrict__ hbf, const int* __restrict__ cursor,
    const int2* __restrict__ epack, const float* __restrict__ We,
    const float* __restrict__ be, const float* __restrict__ epsp, int layer,
    unsigned short* __restrict__ xbf) {
    const int wave = threadIdx.x >> 6, lane = threadIdx.x & 63;
    const int node = __builtin_amdgcn_readfirstlane(blockIdx.x * 4 + wave);
    const int sub = lane >> 5;           // which edge of the pair
    const int dp = (lane & 31) * 8;      // this lane's 8 dims
    float4 wa = *(const float4*)(We + dp);
    float4 wc = *(const float4*)(We + dp + 4);
    float4 b0 = *(const float4*)(be + dp);
    float4 b1 = *(const float4*)(be + dp + 4);
    float w[8]  = {wa.x, wa.y, wa.z, wa.w, wc.x, wc.y, wc.z, wc.w};
    float bv[8] = {b0.x, b0.y, b0.z, b0.w, b1.x, b1.y, b1.z, b1.w};
    float acc[8];
    #pragma unroll
    for (int i = 0; i < 8; ++i) acc[i] = 0.f;
    const unsigned short* hb = hbf + dp;
    const int lo = node * CAP;
    const int cnt = min(__builtin_amdgcn_readfirstlane(cursor[node]) - lo, CAP);
    const int2* ep = epack + lo;
    int t = 0;
#define PAIR(pa, pb) { \
    int s = sub ? (pb).x : (pa).x; \
    float l = __int_as_float(sub ? (pb).y : (pa).y); \
    bf8_t a = *(const bf8_t*)(hb + (size_t)s * DIM); \
    _Pragma("unroll") \
    for (int d = 0; d < 8; ++d) \
        acc[d] += fmaxf(bf2f((unsigned short)a[d]) + fmaf(l, w[d], bv[d]), 0.f); }
    for (; t + 7 < cnt; t += 8) {
        int2 q0 = ep[t + 0], q1 = ep[t + 1], q2 = ep[t + 2], q3 = ep[t + 3];
        int2 q4 = ep[t + 4], q5 = ep[t + 5], q6 = ep[t + 6], q7 = ep[t + 7];
        PAIR(q0, q1) PAIR(q2, q3) PAIR(q4, q5) PAIR(q6, q7)
    }
    for (; t + 1 < cnt; t += 2) {
        int2 q0 = ep[t], q1 = ep[t + 1];
        PAIR(q0, q1)
    }
    if (t < cnt) {     // odd tail: only sub==0 contributes
        int2 q0 = ep[t];
        float l = __int_as_float(q0.y);
        bf8_t a = *(const bf8_t*)(hb + (size_t)q0.x * DIM);
        if (sub == 0) {
            #pragma unroll
            for (int d = 0; d < 8; ++d)
                acc[d] += fmaxf(bf2f((unsigned short)a[d]) + fmaf(l, w[d], bv[d]), 0.f);
        }
    }
#undef PAIR
    // combine the two half-wave partials (same dims, different edges)
    #pragma unroll
    for (int d = 0; d < 8; ++d)
        acc[d] += __shfl(acc[d], lane ^ 32, 64);
    if (sub == 0) {
        const float eps1 = 1.f + epsp[layer];
        bf8_t hv = *(const bf8_t*)(hbf + (size_t)node * DIM + dp);
        bf8_t o;
        #pragma unroll
        for (int d = 0; d < 8; ++d)
            o[d] = (short)f2bf(fmaf(eps1, bf2f((unsigned short)hv[d]), acc[d]));
        *(bf8_t*)(xbf + (size_t)node * DIM + dp) = o;
    }
}

// ---------- MFMA node update: block = 16 rows x 128 cols (grid 1250) ----------
#define XST 264   // LDS row stride (ushorts)
__global__ __launch_bounds__(256) void update_k(
    const unsigned short* __restrict__ xbf,
    const unsigned short* __restrict__ WT, const float* __restrict__ b,
    unsigned short* __restrict__ hout,
    const int* __restrict__ gid, float* __restrict__ feat, int do_pool) {
    __shared__ unsigned short xs[16 * XST];
    __shared__ int gids[16];
    const int rb = blockIdx.x >> 1;
    const int halfc = blockIdx.x & 1;
    const int base = rb * 16;
    const int tid = threadIdx.x;
    #pragma unroll
    for (int cch = tid; cch < 512; cch += 256) {     // 16 rows x 32 chunks of 8
        int rr = cch >> 5, k0 = (cch & 31) * 8;
        *(bf8_t*)&xs[rr * XST + k0] = *(const bf8_t*)(xbf + (size_t)(base + rr) * DIM + k0);
    }
    if (do_pool && tid < 16) gids[tid] = gid[base + tid];
    __syncthreads();
    const int wave = tid >> 6, lane = tid & 63;
    const int m = lane & 15, quad = lane >> 4;
    bf8_t afrag[8];
    #pragma unroll
    for (int s = 0; s < 8; ++s)
        afrag[s] = *(const bf8_t*)&xs[m * XST + s * 32 + quad * 8];
    const int colbase = halfc * 128 + wave * 32;
    f4_t acc[2];
    #pragma unroll
    for (int ct = 0; ct < 2; ++ct) acc[ct] = (f4_t){0.f, 0.f, 0.f, 0.f};
    #pragma unroll
    for (int ct = 0; ct < 2; ++ct) {
        const unsigned short* wp = WT + (size_t)(colbase + ct * 16 + m) * DIM + quad * 8;
        #pragma unroll
        for (int s = 0; s < 8; ++s) {
            bf8_t bfrag = *(const bf8_t*)(wp + s * 32);
            acc[ct] = __builtin_amdgcn_mfma_f32_16x16x32_bf16(afrag[s], bfrag, acc[ct], 0, 0, 0);
        }
    }
    if (!do_pool) {
        #pragma unroll
        for (int ct = 0; ct < 2; ++ct) {
            int col = colbase + ct * 16 + m;
            float bb = b[col];
            #pragma unroll
            for (int r = 0; r < 4; ++r)
                hout[(size_t)(base + quad * 4 + r) * DIM + col] = f2bf(acc[ct][r] + bb);
        }
    } else {
        #pragma unroll
        for (int ct = 0; ct < 2; ++ct) {
            int col = colbase + ct * 16 + m;
            float bb = b[col];
            float run = 0.f;
            int cur = gids[quad * 4];
            #pragma unroll
            for (int r = 0; r < 4; ++r) {
                int g = gids[quad * 4 + r];
                if (g != cur) {
                    atomicAdd(&feat[(size_t)cur * DIM + col], run);
                    run = 0.f;
                    cur = g;
                }
                run += acc[ct][r] + bb;
            }
            atomicAdd(&feat[(size_t)cur * DIM + col], run);
        }
    }
}

// ---------- fused global minmax + normalize + head (one block per graph) ----------
__global__ __launch_bounds__(256) void headmm_k(
    const float* __restrict__ feat, const float* __restrict__ Wm,
    const float* __restrict__ bm, const float* __restrict__ epsp,
    float* __restrict__ out) {
    __shared__ float frow[DIM];
    __shared__ float smn[4], smx[4], sMn, sMx;
    const int g = blockIdx.x;
    const int tid = threadIdx.x;
    float mn = 3.4e38f, mx = -3.4e38f;
    for (int i = tid; i < N_GRAPHS * DIM; i += 256) {
        float v = feat[i];
        mn = fminf(mn, v);
        mx = fmaxf(mx, v);
    }
    frow[tid] = feat[g * DIM + tid];
    #pragma unroll
    for (int off = 32; off > 0; off >>= 1) {
        mn = fminf(mn, __shfl_down(mn, off, 64));
        mx = fmaxf(mx, __shfl_down(mx, off, 64));
    }
    const int wave = tid >> 6, lane = tid & 63;
    if (lane == 0) { smn[wave] = mn; smx[wave] = mx; }
    __syncthreads();
    if (tid == 0) {
        sMn = fminf(fminf(smn[0], smn[1]), fminf(smn[2], smn[3]));
        sMx = fmaxf(fmaxf(smx[0], smx[1]), fmaxf(smx[2], smx[3]));
    }
    __syncthreads();
    if (tid < OUTD) {
        const float mnv = sMn;
        const float inv = 1.f / (epsp[0] + sMx - mnv);
        float acc = 0.f;
        for (int d = 0; d < DIM; ++d)
            acc += (frow[d] - mnv) * Wm[d * OUTD + tid];
        out[g * OUTD + tid] = acc * inv + bm[tid];
    }
}

extern "C" void kernel_launch(void* const* d_in, const int* in_sizes, int n_in,
                              void* d_out, int out_size, void* d_ws, size_t ws_size,
                              hipStream_t stream) {
    const float* atomic_num = (const float*)d_in[0];
    const float* length     = (const float*)d_in[1];
    const int*   src        = (const int*)d_in[2];
    const int*   dst        = (const int*)d_in[3];
    const int*   gid        = (const int*)d_in[4];
    const float* W_node     = (const float*)d_in[5];
    const float* b_node     = (const float*)d_in[6];
    const float* W_edge     = (const float*)d_in[7];
    const float* b_edge     = (const float*)d_in[8];
    const float* gine_eps   = (const float*)d_in[9];
    const float* W_gnn      = (const float*)d_in[10];
    const float* b_gnn      = (const float*)d_in[11];
    const float* eps_param  = (const float*)d_in[12];
    const float* W_mlp      = (const float*)d_in[13];
    const float* b_mlp      = (const float*)d_in[14];
    float* out = (float*)d_out;

    // workspace (~31 MB)
    float* feat = (float*)d_ws;                               // G*D
    int* cursor = (int*)(feat + (size_t)N_GRAPHS * DIM);      // N
    int2* epack = (int2*)(cursor + N_NODES + 4);              // N*CAP
    unsigned short* hbf0 = (unsigned short*)(epack + (size_t)N_NODES * CAP); // [N][256]
    unsigned short* hbf1 = hbf0 + (size_t)N_NODES * DIM;      // [N][256]
    unsigned short* xbf  = hbf1 + (size_t)N_NODES * DIM;      // [N][256]
    unsigned short* WnT  = xbf + (size_t)N_NODES * DIM;       // 256*128
    unsigned short* WgT  = WnT + 256 * 128;                   // 2*256*256

    convW_k<<<640, 256, 0, stream>>>(W_node, W_gnn, WnT, WgT, cursor, feat);
    fill_k<<<N_EDGES / 256, 256, 0, stream>>>(src, dst, length, cursor, epack);
    node_embed_k<<<N_NODES / 16, 256, 0, stream>>>(atomic_num, WnT, b_node, hbf0);

    // GINE layer 0: hbf0 -> xbf -> hbf1
    gather_k<<<N_NODES / 4, 256, 0, stream>>>(
        hbf0, cursor, epack, W_edge, b_edge, gine_eps, 0, xbf);
    update_k<<<(N_NODES / 16) * 2, 256, 0, stream>>>(
        xbf, WgT, b_gnn, hbf1, gid, feat, 0);
    // GINE layer 1: hbf1 -> xbf -> feat (pooled)
    gather_k<<<N_NODES / 4, 256, 0, stream>>>(
        hbf1, cursor, epack, W_edge, b_edge, gine_eps, 1, xbf);
    update_k<<<(N_NODES / 16) * 2, 256, 0, stream>>>(
        xbf, WgT + 256 * 256, b_gnn + DIM, hbf0, gid, feat, 1);

    // fused minmax + normalize + head
    headmm_k<<<N_GRAPHS, 256, 0, stream>>>(feat, W_mlp, b_mlp, eps_param, out);
}